// Round 9
// baseline (357.915 us; speedup 1.0000x reference)
//
#include <hip/hip_runtime.h>
#include <hip/hip_bf16.h>

typedef __bf16 bf16x8 __attribute__((ext_vector_type(8)));
typedef float f32x4 __attribute__((ext_vector_type(4)));
typedef unsigned short ushort_t;

#define S_LEN 4096
#define D_DIM 512
#define NBATCH 4
#define NROW (NBATCH * S_LEN)
#define QKSTR 1024   // fused QK buffer row stride (Q cols 0-511, K cols 512-1023)

static __device__ __forceinline__ ushort_t f2bf(float f) {
    __hip_bfloat16 h = __float2bfloat16(f);
    return __builtin_bit_cast(ushort_t, h);
}

typedef unsigned int __attribute__((address_space(1))) as1_uint;
typedef unsigned int __attribute__((address_space(3))) as3_uint;

// async 16B/lane global->LDS (wave-uniform LDS base + lane*16; global src per-lane)
static __device__ __forceinline__ void gll16(const ushort_t* src, ushort_t* dst) {
    __builtin_amdgcn_global_load_lds((const as1_uint*)(const void*)src,
                                     (as3_uint*)(void*)dst, 16, 0, 0);
}

// ---------------- fp32 -> bf16 convert (with optional scale) ----------------
__global__ void cvt_bf16_kernel(const float* __restrict__ src, ushort_t* __restrict__ dst,
                                int n4, float scale) {
    int i = blockIdx.x * blockDim.x + threadIdx.x;
    if (i >= n4) return;
    float4 v = reinterpret_cast<const float4*>(src)[i];
    ushort4 o;
    o.x = f2bf(v.x * scale);
    o.y = f2bf(v.y * scale);
    o.z = f2bf(v.z * scale);
    o.w = f2bf(v.w * scale);
    reinterpret_cast<ushort4*>(dst)[i] = o;
}

// ---------------- generic bf16 GEMM: C[M][N] = A[M][K] * Bt[N][K]^T ----------------
__global__ __launch_bounds__(256) void gemm_bt(const ushort_t* __restrict__ A,
                                               const ushort_t* __restrict__ Bt,
                                               ushort_t* __restrict__ C,
                                               int M, int N, int K) {
    __shared__ ushort_t As[128 * 40];
    __shared__ ushort_t Bs[128 * 40];
    int tid = threadIdx.x;
    int w = tid >> 6, lane = tid & 63, c = lane & 15, g = lane >> 4;
    int m0 = blockIdx.x * 128, n0 = blockIdx.y * 128;
    int wm = (w >> 1) * 64, wn = (w & 1) * 64;

    f32x4 acc[4][4];
#pragma unroll
    for (int mi = 0; mi < 4; mi++)
#pragma unroll
        for (int ni = 0; ni < 4; ni++) acc[mi][ni] = (f32x4){0.f, 0.f, 0.f, 0.f};

    for (int k0 = 0; k0 < K; k0 += 32) {
        __syncthreads();
#pragma unroll
        for (int r = 0; r < 2; r++) {
            int cl = r * 256 + tid;
            int row = cl >> 2, cin = cl & 3;
            *(bf16x8*)(&As[row * 40 + cin * 8]) =
                *(const bf16x8*)(A + (size_t)(m0 + row) * K + k0 + cin * 8);
            *(bf16x8*)(&Bs[row * 40 + cin * 8]) =
                *(const bf16x8*)(Bt + (size_t)(n0 + row) * K + k0 + cin * 8);
        }
        __syncthreads();

        bf16x8 af[4], bfr[4];
#pragma unroll
        for (int i2 = 0; i2 < 4; i2++)
            af[i2] = *(const bf16x8*)(&As[(wm + i2 * 16 + c) * 40 + g * 8]);
#pragma unroll
        for (int i2 = 0; i2 < 4; i2++)
            bfr[i2] = *(const bf16x8*)(&Bs[(wn + i2 * 16 + c) * 40 + g * 8]);
#pragma unroll
        for (int mi = 0; mi < 4; mi++)
#pragma unroll
            for (int ni = 0; ni < 4; ni++)
                acc[mi][ni] = __builtin_amdgcn_mfma_f32_16x16x32_bf16(af[mi], bfr[ni],
                                                                      acc[mi][ni], 0, 0, 0);
    }

#pragma unroll
    for (int mi = 0; mi < 4; mi++)
#pragma unroll
        for (int ni = 0; ni < 4; ni++)
#pragma unroll
            for (int j = 0; j < 4; j++)
                C[(size_t)(m0 + wm + mi * 16 + g * 4 + j) * N + n0 + wn + ni * 16 + c] =
                    f2bf(acc[mi][ni][j]);
}

// ------------- flash attention: WG-level D-split, direct output, no merge -------------
// 256 WGs of 512 threads, exact balance. WG (b, p, dh): q-blocks j=p then 63-p (130 tiles
// of KVB=32 total); owns D-half dh (softmax recomputed per dh, output written directly).
// Waves (r 0..3, dq 0..1): both dq compute swapped QK^T for rows r*16.. (q = lane&15);
// per-lane scalar softmax; P wave-private in LDS (no barrier); PV on D-quarter dq.
// K/V double-buffered via global_load_lds, both-sides XOR swizzles. 1 barrier/tile.
#define KVB 32
#define PPAD 40

__global__ __launch_bounds__(512, 2) void attn_kernel(const ushort_t* __restrict__ QK,
                                                      const ushort_t* __restrict__ Vt,
                                                      float* __restrict__ out) {
    __shared__ ushort_t Ks[2][KVB][512];      // 64 KB (chunk-swizzled: pos = ch ^ (row&7))
    __shared__ ushort_t Vs[2][256][KVB];      // 32 KB (chunk-swizzled: pos = ch ^ hash(row&15))
    __shared__ ushort_t Ps[8 * 16 * PPAD];    // 10 KB, per-wave private

    const int gid = blockIdx.x;
    const int b = gid & 3;
    const int dh = (gid >> 2) & 1;     // D-half of the output this WG owns
    const int p = gid >> 3;            // 0..31 -> q-block pair (p, 63-p)
    const int tid = threadIdx.x;
    const int w = tid >> 6, lane = tid & 63, c = lane & 15, g = lane >> 4;
    const int r = w & 3, dq = w >> 2;  // row-group, D-quarter within the half

    const ushort_t* Q  = QK;           // cols 0-511 of fused buffer
    const ushort_t* Kp = QK + 512;     // cols 512-1023

    const int sbase = b * S_LEN;
    ushort_t* pw = Ps + w * 16 * PPAD;
    const int hc = (c ^ (c >> 2)) & 3;            // V-read swizzle hash
    const int vrr = lane >> 2, vpc = lane & 3;    // V-stage row/chunk within 16-row group
    const int vhh = (vrr ^ (vrr >> 2)) & 3;       // V-stage swizzle hash

    for (int phase = 0; phase < 2; ++phase) {
        const int jblk = phase ? (63 - p) : p;
        const int qbase = jblk * 64;
        const int tlast = 2 * jblk + 1;

        // Q fragments (1/sqrt(512) folded into W_q); dq-pair waves load the same 16 rows.
        bf16x8 qf[16];
        {
            const ushort_t* qrow = Q + (size_t)(sbase + qbase + r * 16 + c) * QKSTR;
#pragma unroll
            for (int kk = 0; kk < 16; kk++)
                qf[kk] = *(const bf16x8*)(qrow + kk * 32 + g * 8);
        }

        f32x4 o[8];
#pragma unroll
        for (int t = 0; t < 8; t++) o[t] = (f32x4){0.f, 0.f, 0.f, 0.f};
        float m_r = -1e30f, l_r = 0.f;   // per-lane: q-row = r*16 + c

        // ---- prologue: stage tile 0 into buf 0 ----
        {
            const ushort_t* kg = Kp + (size_t)sbase * QKSTR;
#pragma unroll
            for (int ii = 0; ii < 4; ii++) {
                int row = w * 4 + ii;
                gll16(kg + (size_t)row * QKSTR + ((lane ^ (row & 7)) * 8), &Ks[0][row][0]);
            }
#pragma unroll
            for (int ii = 0; ii < 2; ii++) {
                int grp = w * 2 + ii;   // 16-row group of this WG's V-half
                gll16(Vt + (size_t)(dh * 256 + grp * 16 + vrr) * NROW + sbase + ((vpc ^ vhh) * 8),
                      &Vs[0][grp * 16][0]);
            }
        }
        __syncthreads();   // buf0 staged (barrier drains vmcnt)

        for (int t = 0; t <= tlast; ++t) {
            const int cur = t & 1;

            // ---- issue async stage of tile t+1 into the other buffer ----
            if (t + 1 <= tlast) {
                const int kv0n = (t + 1) * KVB;
                const ushort_t* kg = Kp + (size_t)(sbase + kv0n) * QKSTR;
#pragma unroll
                for (int ii = 0; ii < 4; ii++) {
                    int row = w * 4 + ii;
                    gll16(kg + (size_t)row * QKSTR + ((lane ^ (row & 7)) * 8),
                          &Ks[cur ^ 1][row][0]);
                }
#pragma unroll
                for (int ii = 0; ii < 2; ii++) {
                    int grp = w * 2 + ii;
                    gll16(Vt + (size_t)(dh * 256 + grp * 16 + vrr) * NROW + sbase + kv0n +
                              ((vpc ^ vhh) * 8),
                          &Vs[cur ^ 1][grp * 16][0]);
                }
            }

            const int kv0 = t * KVB;

            // ---- swapped QK^T : S^T[kv][q], every wave, own 16 q-rows ----
            f32x4 s4[2];
#pragma unroll
            for (int nt = 0; nt < 2; nt++) {
                f32x4 acc = (f32x4){0.f, 0.f, 0.f, 0.f};
#pragma unroll
                for (int kk = 0; kk < 16; kk++) {
                    bf16x8 kf = *(const bf16x8*)(
                        &Ks[cur][nt * 16 + c][((4 * kk + g) ^ (c & 7)) * 8]);
                    acc = __builtin_amdgcn_mfma_f32_16x16x32_bf16(kf, qf[kk], acc, 0, 0, 0);
                }
                s4[nt] = acc;   // s4[nt][jj] = S[kv0 + nt*16 + g*4 + jj][q = r*16 + c]
            }

            // ---- causal mask (diagonal 64-block = last two KVB-32 tiles) ----
            if (t >= 2 * jblk) {
                int qrow = qbase + r * 16 + c;
#pragma unroll
                for (int nt = 0; nt < 2; nt++)
#pragma unroll
                    for (int jj = 0; jj < 4; jj++) {
                        int kvcol = kv0 + nt * 16 + g * 4 + jj;
                        if (kvcol > qrow) s4[nt][jj] = -1e38f;
                    }
            }

            // ---- per-lane online softmax (row q = r*16+c spread over 4 g-groups) ----
            float pm = s4[0][0];
#pragma unroll
            for (int jj = 1; jj < 4; jj++) pm = fmaxf(pm, s4[0][jj]);
#pragma unroll
            for (int jj = 0; jj < 4; jj++) pm = fmaxf(pm, s4[1][jj]);
            pm = fmaxf(pm, __shfl_xor(pm, 16, 64));
            pm = fmaxf(pm, __shfl_xor(pm, 32, 64));
            float mn = fmaxf(m_r, pm);
            float alpha = __expf(m_r - mn);   // == 1.0f exactly when max unchanged
            m_r = mn;

            float pv[2][4], rs = 0.f;
#pragma unroll
            for (int nt = 0; nt < 2; nt++)
#pragma unroll
                for (int jj = 0; jj < 4; jj++) {
                    pv[nt][jj] = __expf(s4[nt][jj] - mn);
                    rs += pv[nt][jj];
                }
            rs += __shfl_xor(rs, 16, 64);
            rs += __shfl_xor(rs, 32, 64);
            l_r = l_r * alpha + rs;

            // ---- pack P to wave-private LDS (no barrier: same-wave write->read) ----
#pragma unroll
            for (int nt = 0; nt < 2; nt++) {
                ushort4 u;
                u.x = f2bf(pv[nt][0]);
                u.y = f2bf(pv[nt][1]);
                u.z = f2bf(pv[nt][2]);
                u.w = f2bf(pv[nt][3]);
                *(ushort4*)(&pw[c * PPAD + nt * 16 + g * 4]) = u;
            }
            bf16x8 pa = *(const bf16x8*)(&pw[c * PPAD + g * 8]);

            // ---- rescale O (wave-uniform skip when all alphas == 1) ----
            if (__any((int)(alpha != 1.f))) {
                float aq[4];
#pragma unroll
                for (int jj = 0; jj < 4; jj++)
                    aq[jj] = __shfl(alpha, (lane & 48) | (g * 4 + jj), 64);
#pragma unroll
                for (int dt = 0; dt < 8; dt++)
#pragma unroll
                    for (int jj = 0; jj < 4; jj++) o[dt][jj] *= aq[jj];
            }

            // ---- PV : O[16 rows][128 cols (dq quarter)] += P[16x32] * V[32x128] ----
#pragma unroll
            for (int dt = 0; dt < 8; dt++) {
                bf16x8 vf = *(const bf16x8*)(&Vs[cur][dq * 128 + dt * 16 + c][(g ^ hc) * 8]);
                o[dt] = __builtin_amdgcn_mfma_f32_16x16x32_bf16(pa, vf, o[dt], 0, 0, 0);
            }

            __syncthreads();   // end of tile: stage(t+1) landed; all reads of buf[cur] done
        }

        // ---- epilogue: normalize and write final output for this q-block / D-quarter ----
        float inv = 1.f / l_r;
        float invq[4];
#pragma unroll
        for (int jj = 0; jj < 4; jj++)
            invq[jj] = __shfl(inv, (lane & 48) | (g * 4 + jj), 64);
#pragma unroll
        for (int dt = 0; dt < 8; dt++)
#pragma unroll
            for (int jj = 0; jj < 4; jj++)
                out[(size_t)(sbase + qbase + r * 16 + g * 4 + jj) * D_DIM +
                    dh * 256 + dq * 128 + dt * 16 + c] = o[dt][jj] * invq[jj];
    }
}

// ---------------- host launch ----------------
extern "C" void kernel_launch(void* const* d_in, const int* in_sizes, int n_in,
                              void* d_out, int out_size, void* d_ws, size_t ws_size,
                              hipStream_t stream) {
    const float* X  = (const float*)d_in[0];
    const float* Wq = (const float*)d_in[1];
    const float* Wk = (const float*)d_in[2];
    const float* Wv = (const float*)d_in[3];
    float* out = (float*)d_out;

    const int M = NROW;             // 16384
    const int Kd = D_DIM;           // 512
    const size_t XBF_BYTES  = (size_t)M * Kd * 2;        // 16.8 MB
    const size_t W_BYTES    = (size_t)Kd * Kd * 2;       // 0.5 MB
    const size_t QK_BYTES   = (size_t)M * QKSTR * 2;     // 33.6 MB

    char* p = (char*)d_ws;
    ushort_t* Xbf  = (ushort_t*)p;             p += XBF_BYTES;
    ushort_t* Wqkb = (ushort_t*)p;             p += 2 * W_BYTES;   // [1024][512]
    ushort_t* Wvb  = (ushort_t*)p;             p += W_BYTES;
    ushort_t* QKb  = (ushort_t*)p;             p += QK_BYTES;      // [16384][1024]
    ushort_t* Vtb  = (ushort_t*)p;             p += XBF_BYTES;     // [512][16384]

    const float qscale = 0.044194173824159216f;  // 1/sqrt(512)

    {
        int n4 = (M * Kd) / 4;
        cvt_bf16_kernel<<<(n4 + 255) / 256, 256, 0, stream>>>(X, Xbf, n4, 1.0f);
        int w4 = (Kd * Kd) / 4;
        cvt_bf16_kernel<<<(w4 + 255) / 256, 256, 0, stream>>>(Wq, Wqkb, w4, qscale);
        cvt_bf16_kernel<<<(w4 + 255) / 256, 256, 0, stream>>>(Wk, Wqkb + Kd * Kd, w4, 1.0f);
        cvt_bf16_kernel<<<(w4 + 255) / 256, 256, 0, stream>>>(Wv, Wvb, w4, 1.0f);
    }
    // fused [Q|K] projection: C[16384][1024] = X * [Wq;Wk]^T
    gemm_bt<<<dim3(M / 128, QKSTR / 128), 256, 0, stream>>>(Xbf, Wqkb, QKb, M, QKSTR, Kd);
    // V^T = Wv * X^T : C[512][16384]
    gemm_bt<<<dim3(Kd / 128, M / 128), 256, 0, stream>>>(Wvb, Xbf, Vtb, Kd, M, Kd);
    // attention, direct normalized output
    attn_kernel<<<256, 512, 0, stream>>>(QKb, Vtb, out);
}